// Round 7
// baseline (194.834 us; speedup 1.0000x reference)
//
#include <hip/hip_runtime.h>
#include <hip/hip_bf16.h>

typedef unsigned short u16;
typedef short short8 __attribute__((ext_vector_type(8)));
typedef float floatx4 __attribute__((ext_vector_type(4)));

#define MFMA16(a, b, c) __builtin_amdgcn_mfma_f32_16x16x32_bf16((a), (b), (c), 0, 0, 0)

union U128u { uint4 q; u16 s[8]; };

__device__ __forceinline__ u16 f2bf(float f) {
  union { float f; unsigned u; } v; v.f = f;
  unsigned r = v.u + 0x7fffu + ((v.u >> 16) & 1u);
  return (u16)(r >> 16);
}

__device__ __forceinline__ float bf2f(u16 s) {
  union { unsigned u; float f; } v; v.u = ((unsigned)s) << 16;
  return v.f;
}

// pack two f32 -> bf16x2 (round-half-up) with one v_perm (attn P only)
__device__ __forceinline__ unsigned pk2(float hi, float lo) {
  union { float f; unsigned u; } a, b;
  a.f = hi; b.f = lo;
  return __builtin_amdgcn_perm(a.u + 0x8000u, b.u + 0x8000u, 0x07060302u);
}

__device__ __forceinline__ float fexp2(float x) {
#if __has_builtin(__builtin_amdgcn_exp2f)
  return __builtin_amdgcn_exp2f(x);
#else
  return exp2f(x);
#endif
}

// async global->LDS, 16B per lane. lds pointer must be wave-uniform. (GEMMs only.)
__device__ __forceinline__ void async16(const u16* g, u16* l) {
  __builtin_amdgcn_global_load_lds(
      (const __attribute__((address_space(1))) unsigned int*)g,
      (__attribute__((address_space(3))) unsigned int*)l, 16, 0, 0);
}

// ---------------- prep: cast x, cast Wo, biases, W repack via LDS TRANSPOSE ----------------
// r7: the old repack stored Wt as scalar u16 at stride 2KB -> ~32x HBM write amplification
// (~100-200 MB effective for 6.3 MB payload). Now: 384 transpose blocks, each reads a
// 128d x 64kk fp32 panel coalesced (float4), stages bf16 in LDS [128][68] (pad 68 breaks
// phase-2 self-conflicts), writes Wt rows as bf16x8 (256B contiguous per 16 lanes).

__global__ __launch_bounds__(256) void prep_all(
    const float* __restrict__ x, const float* __restrict__ Wo,
    const float* __restrict__ Wq, const float* __restrict__ bq,
    const float* __restrict__ Wk, const float* __restrict__ bk,
    const float* __restrict__ Wv, const float* __restrict__ bv,
    u16* __restrict__ Xb, u16* __restrict__ Wob,
    u16* __restrict__ Wt, float* __restrict__ ball) {
  __shared__ __attribute__((aligned(16))) u16 T[128 * 68];  // transpose staging (17 KB)
  int bid = blockIdx.x;
  int tid = threadIdx.x;
  if (bid < 5120) {
    // cast: blocks [0,4096) -> x (1048576 float4), [4096,5120) -> Wo (262144 float4)
    const float* src = bid < 4096 ? x : Wo;
    u16* dst = bid < 4096 ? Xb : Wob;
    int i = (bid < 4096 ? bid : bid - 4096) * 256 + tid;
    float4 v = ((const float4*)src)[i];
    union { unsigned long long ll; u16 s[4]; } o;
    o.s[0] = f2bf(v.x); o.s[1] = f2bf(v.y); o.s[2] = f2bf(v.z); o.s[3] = f2bf(v.w);
    ((unsigned long long*)dst)[i] = o.ll;
    return;
  }
  if (bid < 5132) {  // bias copy: 12 blocks x 256 = 3072
    int id = (bid - 5120) * 256 + tid;
    int ws2 = id >> 10, hk = id & 1023;
    const float* bsrc = ws2 == 0 ? bq : (ws2 == 1 ? bk : bv);
    ball[id] = bsrc[hk];
    return;
  }
  // W transpose: tb in [0,384) = wsel(3) x h(16) x dblk(8)
  int tb = bid - 5132;
  int wsel = tb >> 7;
  int rem = tb & 127;
  int h = rem >> 3, dblk = rem & 7;
  const float* W = wsel == 0 ? Wq : (wsel == 1 ? Wk : Wv);
  const int d0 = dblk * 128;
  // phase 1: coalesced read [128 d][64 kk] fp32 -> LDS bf16 [d][kk] (row stride 68)
#pragma unroll
  for (int k = 0; k < 8; ++k) {
    int slot = k * 256 + tid;        // 2048 slots = 128 rows x 16 float4
    int d = slot >> 4, c4 = slot & 15;
    float4 v = *(const float4*)(W + ((size_t)(h * 1024 + d0 + d)) * 64 + c4 * 4);
    union { unsigned long long ll; u16 s[4]; } o;
    o.s[0] = f2bf(v.x); o.s[1] = f2bf(v.y); o.s[2] = f2bf(v.z); o.s[3] = f2bf(v.w);
    *(unsigned long long*)(T + d * 68 + c4 * 4) = o.ll;
  }
  __syncthreads();
  // phase 2: write Wt[n = wsel*1024 + h*64 + kk][d0 + dc*8 .. +8] as bf16x8
#pragma unroll
  for (int k = 0; k < 4; ++k) {
    int slot = k * 256 + tid;        // 1024 slots = 64 kk x 16 d-chunks
    int kk = slot >> 4, dc = slot & 15;
    U128u o;
#pragma unroll
    for (int j = 0; j < 8; ++j) o.s[j] = T[(dc * 8 + j) * 68 + kk];
    int n = wsel * 1024 + h * 64 + kk;
    *(uint4*)(Wt + (size_t)n * 1024 + d0 + dc * 8) = o.q;
  }
}

// ---------------- GEMM: C[M,N] = A[M,K] * B^T (B stored [N,K]) + bias, opt scale --------------
// (QKV projection only now; out-proj moved to gemm_out64 for 4 blocks/CU.)

__device__ __forceinline__ void store_out(u16* p, float v) { *p = f2bf(v); }
__device__ __forceinline__ void store_out(float* p, float v) { *p = v; }

template <int BN, bool SPLITV, bool TRANS, typename OutT>
__global__ __launch_bounds__(256, 4) void gemm_bt(
    const u16* __restrict__ A, const u16* __restrict__ B,
    const float* __restrict__ bias, OutT* __restrict__ C,
    u16* __restrict__ Vtc,
    int M, int N, int K, int scaleNend, float scaleVal) {
  constexpr int TN = BN / 32;  // n-tiles per wave
  __shared__ __attribute__((aligned(16))) u16 As[128 * 64];
  __shared__ __attribute__((aligned(16))) u16 Bs[BN * 64];
  const int tid = threadIdx.x;
  const int w = tid >> 6, lane = tid & 63;
  const int l15 = lane & 15, l4 = lane >> 4;
  const int lin = blockIdx.x;
  const int xcd = lin & 7, sblk = lin >> 3;
  const int bm = xcd * 4 + (sblk & 3);   // M=4096 -> 32 bm tiles, 4 per XCD
  const int bn = sblk >> 2;
  const int wm = (w & 1) * 64, wn = (w >> 1) * (BN / 2);

  floatx4 acc[4][TN];
#pragma unroll
  for (int i = 0; i < 4; ++i)
#pragma unroll
    for (int j = 0; j < TN; ++j) acc[i][j] = (floatx4){0.f, 0.f, 0.f, 0.f};

  for (int k0 = 0; k0 < K; k0 += 64) {
    __syncthreads();
#pragma unroll
    for (int j = 0; j < 4; ++j) {  // A: 128 rows x 8 chunks = 1024 slots
      int i = j * 256 + tid;
      int row = i >> 3, c = (i & 7) ^ (row & 7);
      async16(A + (size_t)(bm * 128 + row) * K + k0 + c * 8, As + (j * 256 + w * 64) * 8);
    }
#pragma unroll
    for (int j = 0; j < BN / 32; ++j) {  // B: BN rows x 8 chunks
      int i = j * 256 + tid;
      int row = i >> 3, c = (i & 7) ^ (row & 7);
      async16(B + (size_t)(bn * BN + row) * K + k0 + c * 8, Bs + (j * 256 + w * 64) * 8);
    }
    __syncthreads();
    const int sw = l15 & 7;
#pragma unroll
    for (int ks = 0; ks < 2; ++ks) {
      short8 af[4], bf[TN];
#pragma unroll
      for (int t = 0; t < 4; ++t)
        af[t] = *(const short8*)(As + (wm + t * 16 + l15) * 64 + (((ks * 4 + l4) ^ sw)) * 8);
#pragma unroll
      for (int t = 0; t < TN; ++t)
        bf[t] = *(const short8*)(Bs + (wn + t * 16 + l15) * 64 + (((ks * 4 + l4) ^ sw)) * 8);
#pragma unroll
      for (int tm = 0; tm < 4; ++tm)
#pragma unroll
        for (int tn = 0; tn < TN; ++tn)
          acc[tm][tn] = TRANS ? MFMA16(bf[tn], af[tm], acc[tm][tn])
                              : MFMA16(af[tm], bf[tn], acc[tm][tn]);
    }
  }

  if (TRANS) {
    // acc holds transposed fragments: lane l15 -> row (A index), l4*4+r -> col (B index)
#pragma unroll
    for (int tn = 0; tn < TN; ++tn) {
      int colb = bn * BN + wn + tn * 16 + l4 * 4;
      float4 bv4 = *(const float4*)(bias + colb);
#pragma unroll
      for (int tm = 0; tm < 4; ++tm) {
        int row = bm * 128 + wm + tm * 16 + l15;
        float4 v;
        v.x = acc[tm][tn][0] + bv4.x;
        v.y = acc[tm][tn][1] + bv4.y;
        v.z = acc[tm][tn][2] + bv4.z;
        v.w = acc[tm][tn][3] + bv4.w;
        *(float4*)((float*)C + (size_t)row * N + colb) = v;
      }
    }
    return;
  }

#pragma unroll
  for (int tn = 0; tn < TN; ++tn) {
    int col = bn * BN + wn + tn * 16 + l15;
    float bv = bias[col];
    float sc = (col < scaleNend) ? scaleVal : 1.0f;
    if (!SPLITV || col < 2048) {
#pragma unroll
      for (int tm = 0; tm < 4; ++tm) {
        int row0 = bm * 128 + wm + tm * 16 + l4 * 4;
#pragma unroll
        for (int r = 0; r < 4; ++r) {
          float v = (acc[tm][tn][r] + bv) * sc;
          store_out(C + (size_t)(row0 + r) * N + col, v);
        }
      }
    } else {
      int hv = (col - 2048) >> 6, d = (col - 2048) & 63;
#pragma unroll
      for (int tm = 0; tm < 4; ++tm) {
        int row0 = bm * 128 + wm + tm * 16 + l4 * 4;
        int bb = row0 >> 11, s0 = row0 & 2047;
        union { unsigned long long ll; u16 s[4]; } o;
#pragma unroll
        for (int r = 0; r < 4; ++r) o.s[r] = f2bf(acc[tm][tn][r] + bv);
        // rows row0..row0+3 are consecutive (s&7) slots of one octet -> one 8B store
        size_t idx = ((((size_t)(bb * 16 + hv) * 128 + (s0 >> 4)) * 2 + ((s0 >> 3) & 1)) * 64 + d) * 8 +
                     (s0 & 7);
        *(unsigned long long*)(Vtc + idx) = o.ll;
      }
    }
  }
}

// ---------------- out-proj GEMM: BM=64, BN=64 -> 1024 blocks = 4 blocks/CU ----------------
__global__ __launch_bounds__(256, 4) void gemm_out64(
    const u16* __restrict__ A, const u16* __restrict__ B,
    const float* __restrict__ bias, float* __restrict__ C) {
  __shared__ __attribute__((aligned(16))) u16 As[64 * 64];
  __shared__ __attribute__((aligned(16))) u16 Bs[64 * 64];
  const int tid = threadIdx.x;
  const int w = tid >> 6, lane = tid & 63;
  const int l15 = lane & 15, l4 = lane >> 4;
  const int lin = blockIdx.x;                // 1024 blocks
  const int xcd = lin & 7, sblk = lin >> 3;  // sblk in [0,128)
  const int bm = xcd * 8 + (sblk & 7);       // 64 bm tiles, 8 per XCD
  const int bn = sblk >> 3;                  // 16 bn tiles
  const int wm = (w & 1) * 32, wn = (w >> 1) * 32;

  floatx4 acc[2][2];
#pragma unroll
  for (int i = 0; i < 2; ++i)
#pragma unroll
    for (int j = 0; j < 2; ++j) acc[i][j] = (floatx4){0.f, 0.f, 0.f, 0.f};

  for (int k0 = 0; k0 < 1024; k0 += 64) {
    __syncthreads();
#pragma unroll
    for (int j = 0; j < 2; ++j) {  // A: 64 rows x 8 chunks = 512 slots
      int i = j * 256 + tid;
      int row = i >> 3, c = (i & 7) ^ (row & 7);
      async16(A + (size_t)(bm * 64 + row) * 1024 + k0 + c * 8, As + (j * 256 + w * 64) * 8);
    }
#pragma unroll
    for (int j = 0; j < 2; ++j) {  // B: 64 rows x 8 chunks
      int i = j * 256 + tid;
      int row = i >> 3, c = (i & 7) ^ (row & 7);
      async16(B + (size_t)(bn * 64 + row) * 1024 + k0 + c * 8, Bs + (j * 256 + w * 64) * 8);
    }
    __syncthreads();
    const int sw = l15 & 7;
#pragma unroll
    for (int ks = 0; ks < 2; ++ks) {
      short8 af[2], bf[2];
#pragma unroll
      for (int t = 0; t < 2; ++t)
        af[t] = *(const short8*)(As + (wm + t * 16 + l15) * 64 + (((ks * 4 + l4) ^ sw)) * 8);
#pragma unroll
      for (int t = 0; t < 2; ++t)
        bf[t] = *(const short8*)(Bs + (wn + t * 16 + l15) * 64 + (((ks * 4 + l4) ^ sw)) * 8);
#pragma unroll
      for (int tm = 0; tm < 2; ++tm)
#pragma unroll
        for (int tn = 0; tn < 2; ++tn)
          acc[tm][tn] = MFMA16(bf[tn], af[tm], acc[tm][tn]);  // TRANS order
    }
  }

  // TRANS epilogue: lane l15 -> C row, l4*4+r -> C col; float4 stores
#pragma unroll
  for (int tn = 0; tn < 2; ++tn) {
    int colb = bn * 64 + wn + tn * 16 + l4 * 4;
    float4 bv4 = *(const float4*)(bias + colb);
#pragma unroll
    for (int tm = 0; tm < 2; ++tm) {
      int row = bm * 64 + wm + tm * 16 + l15;
      float4 v;
      v.x = acc[tm][tn][0] + bv4.x;
      v.y = acc[tm][tn][1] + bv4.y;
      v.z = acc[tm][tn][2] + bv4.z;
      v.w = acc[tm][tn][3] + bv4.w;
      *(float4*)(C + (size_t)row * 1024 + colb) = v;
    }
  }
}

// ---------------- attention v7: r5 skew + l-SUM VIA MFMA ONES-COLUMN ----------------
// OCCUPANCY VERDICT (r1/r3/r4): 64q x 512k wave tile needs ~148-160 regs; 12 waves/CU is
// the ceiling. TILING (r2): smaller wave tiles halve K/V reuse; 1.8x worse. SKEW (r5):
// S^T(c) -> P-buf[c&1] while PV(c-1) drains the other; +6 us. PREFETCH (r6): kf register
// prefetch NULL (+scratch traffic) -- at this register pressure, pipeline state is
// self-defeating. Reverted to r5 loop shape.
// THIS ROUND: issue-work audit: ~340 VALU cyc vs 160 MFMA cyc per superstep. The lpart
// add-chain (32 VALU/superstep + end shfl-reduce) moves to the matrix pipe: vone = B-frag
// of a "ones column" (1.0 at l15==0); acc_l[tq] = MFMA(pf[tq], vone, acc_l[tq]) puts
// sum_k P[q,k] in column 0 (rows q = tq*16+l4*4+r at lanes l15==0). 4 extra MFMAs
// (~20 cyc) replace ~70 VALU cyc. +16 AGPR, -4 VGPR -> ~160 <= 168 (3-wave quantum).
// l now sums bf16-rounded P -- consistent with the PV numerator rounding.
// GATE: WRITE ~8.2 MB / FETCH ~12.6 MB. If ballooned -> revert ones-trick.
__global__ __launch_bounds__(256, 3) void attn_kernel(const u16* __restrict__ QKV,
                                                      const u16* __restrict__ Vtc,
                                                      u16* __restrict__ Ob) {
  // per-wave region: 5120 u16 = P double-buffer [2][64 q][stride 40] (2x2560),
  // overlaid post-loop by Osum bf16 [64][stride 72] (4608) + l f32[64] at 4608.
  __shared__ __attribute__((aligned(16))) u16 lds[4 * 5120];  // 40960 B
  const int tid = threadIdx.x;
  const int w = tid >> 6, lane = tid & 63;
  const int l15 = lane & 15, l4 = lane >> 4;
  const int lin = blockIdx.x;                 // 1024 blocks
  const int xcd = lin & 7, sblk = lin >> 3;   // sblk in [0,128)
  const int bh = xcd * 4 + (sblk & 3);        // 4 bh per XCD
  const int q0 = (sblk >> 2) * 64;            // 32 q-tiles of 64
  const int b = bh >> 4, h = bh & 15;

  u16* const Pw = lds + w * 5120;

  // Q fragments (B-operand of S^T): rows q0 + tq*16 + l15, k(d) = s*32 + l4*8
  short8 qf[4][2];
  {
    const u16* Qb = QKV + (size_t)(b * 2048 + q0) * 3072 + h * 64;
#pragma unroll
    for (int tq = 0; tq < 4; ++tq)
#pragma unroll
      for (int s = 0; s < 2; ++s)
        qf[tq][s] = *(const short8*)(Qb + (size_t)(tq * 16 + l15) * 3072 + s * 32 + l4 * 8);
  }

  floatx4 Oacc[4][4];
#pragma unroll
  for (int i = 0; i < 4; ++i)
#pragma unroll
    for (int j = 0; j < 4; ++j) Oacc[i][j] = (floatx4){0.f, 0.f, 0.f, 0.f};
  floatx4 acc_l[4];
#pragma unroll
  for (int i = 0; i < 4; ++i) acc_l[i] = (floatx4){0.f, 0.f, 0.f, 0.f};

  // ones-column B fragment: B[n][k] = 1.0 iff n == 0 (lane n = l15, k = l4*8+j)
  short8 vone;
  {
    u16 one = (l15 == 0) ? (u16)0x3F80 : (u16)0;
#pragma unroll
    for (int j = 0; j < 8; ++j) vone[j] = (short)one;
  }

  const u16* const Kb = QKV + (size_t)(b * 2048) * 3072 + 1024 + h * 64;  // + key*3072
  const u16* const Vw = Vtc + (size_t)bh * 131072 + (size_t)w * 32768;    // wave's 512 keys
  const int kw0 = w * 512;

  // ---- S^T for one 32-key superstep c into P buffer pb ----
  auto do_st = [&](int c, u16* pb) {
    const int key0 = kw0 + c * 32;
    short8 kf[2][2];
#pragma unroll
    for (int t = 0; t < 2; ++t)
#pragma unroll
      for (int s = 0; s < 2; ++s)
        kf[t][s] = *(const short8*)(Kb + (size_t)(key0 + t * 16 + l15) * 3072 + s * 32 + l4 * 8);
#pragma unroll
    for (int t = 0; t < 2; ++t)
#pragma unroll
      for (int tq = 0; tq < 4; ++tq) {
        floatx4 s = (floatx4){0.f, 0.f, 0.f, 0.f};
        s = MFMA16(kf[t][0], qf[tq][0], s);
        s = MFMA16(kf[t][1], qf[tq][1], s);
        float p0 = fexp2(s[0]), p1 = fexp2(s[1]), p2 = fexp2(s[2]), p3 = fexp2(s[3]);
        unsigned lo = pk2(p1, p0), hi = pk2(p3, p2);
        *(unsigned long long*)(pb + (size_t)(tq * 16 + l15) * 40 + t * 16 + l4 * 4) =
            ((unsigned long long)hi << 32) | lo;
      }
  };

  // ---- PV for superstep c from P buffer pb; l-sum rides the matrix pipe ----
  auto do_pv = [&](int c, const u16* pb) {
    short8 vf[4];
#pragma unroll
    for (int td = 0; td < 4; ++td)
      vf[td] = *(const short8*)(Vw + (size_t)c * 2048 + l4 * 512 + (td * 16 + l15) * 8);
    short8 pf[4];
#pragma unroll
    for (int tq = 0; tq < 4; ++tq)
      pf[tq] = *(const short8*)(pb + (size_t)(tq * 16 + l15) * 40 + l4 * 8);
#pragma unroll
    for (int td = 0; td < 4; ++td)
#pragma unroll
      for (int tq = 0; tq < 4; ++tq) Oacc[tq][td] = MFMA16(pf[tq], vf[td], Oacc[tq][td]);
#pragma unroll
    for (int tq = 0; tq < 4; ++tq) acc_l[tq] = MFMA16(pf[tq], vone, acc_l[tq]);
  };

  // prologue: fill P buffer 0
  do_st(0, Pw);
  // steady state: S^T(c) -> buf[c&1] while PV(c-1) drains buf[(c-1)&1]
#pragma unroll 1
  for (int c = 1; c < 16; ++c) {
    do_st(c, Pw + (c & 1) * 2560);
    do_pv(c - 1, Pw + ((c - 1) & 1) * 2560);
  }
  // epilogue
  do_pv(15, Pw + 2560);

  // write per-wave partials (own region; own P reads already retired in-order)
#pragma unroll
  for (int tq = 0; tq < 4; ++tq)
#pragma unroll
    for (int td = 0; td < 4; ++td)
#pragma unroll
      for (int r = 0; r < 4; ++r)
        Pw[(size_t)(tq * 16 + l4 * 4 + r) * 72 + td * 16 + l15] = f2bf(Oacc[tq][td][r]);
  if (l15 == 0) {  // acc_l column 0 lives in lanes l15==0; rows q = tq*16 + l4*4 + r
    float* Lw = (float*)(Pw + 4608);
#pragma unroll
    for (int tq = 0; tq < 4; ++tq)
#pragma unroll
      for (int r = 0; r < 4; ++r) Lw[tq * 16 + l4 * 4 + r] = acc_l[tq][r];
  }
  __syncthreads();

  // combine: thread -> (row = tid>>2 of 64, 16 cols); sum 4 wave partials
  {
    int row = tid >> 2, c0 = (tid & 3) * 16;
    float acc[16];
#pragma unroll
    for (int j = 0; j < 16; ++j) acc[j] = 0.f;
    float lsum = 0.f;
#pragma unroll
    for (int wv = 0; wv < 4; ++wv) {
      const u16* R = lds + wv * 5120;
      lsum += ((const float*)(R + 4608))[row];
      U128u x1, x2;
      x1.q = *(const uint4*)(R + (size_t)row * 72 + c0);
      x2.q = *(const uint4*)(R + (size_t)row * 72 + c0 + 8);
#pragma unroll
      for (int j = 0; j < 8; ++j) { acc[j] += bf2f(x1.s[j]); acc[8 + j] += bf2f(x2.s[j]); }
    }
    float inv = 1.0f / lsum;
    U128u o1, o2;
#pragma unroll
    for (int j = 0; j < 8; ++j) { o1.s[j] = f2bf(acc[j] * inv); o2.s[j] = f2bf(acc[8 + j] * inv); }
    u16* Op = Ob + (size_t)(b * 2048 + q0 + row) * 1024 + h * 64 + c0;
    *(uint4*)Op = o1.q;
    *(uint4*)(Op + 8) = o2.q;
  }
}

// ---------------- launch ----------------

extern "C" void kernel_launch(void* const* d_in, const int* in_sizes, int n_in,
                              void* d_out, int out_size, void* d_ws, size_t ws_size,
                              hipStream_t stream) {
  const float* x  = (const float*)d_in[0];
  const float* Wq = (const float*)d_in[1];
  const float* bq = (const float*)d_in[2];
  const float* Wk = (const float*)d_in[3];
  const float* bk = (const float*)d_in[4];
  const float* Wv = (const float*)d_in[5];
  const float* bv = (const float*)d_in[6];
  const float* Wo = (const float*)d_in[7];
  const float* bo = (const float*)d_in[8];

  char* p = (char*)d_ws;
  u16* Xb   = (u16*)p; p += (size_t)4096 * 1024 * 2;   // x bf16
  u16* Wt   = (u16*)p; p += (size_t)3072 * 1024 * 2;   // W_all^T bf16 [n][d]
  u16* QKV  = (u16*)p; p += (size_t)4096 * 3072 * 2;   // [token][3072] bf16; Q pre-scaled, V third unused
  u16* Vtc  = (u16*)p; p += (size_t)32 * 128 * 2 * 64 * 8 * 2;  // V chunked: [bh][v][o][d][k8]
  u16* Ob   = (u16*)p; p += (size_t)4096 * 1024 * 2;   // attention out bf16 (normalized)
  u16* Wob  = (u16*)p; p += (size_t)1024 * 1024 * 2;   // Wo bf16 [e][d]
  float* ball = (float*)p; p += 3072 * sizeof(float);

  const float qscale = 0.125f * 1.4426950408889634f;  // (1/sqrt(64)) * log2(e)

  // prep: 5120 cast + 12 bias + 384 transpose = 5516 blocks
  prep_all<<<5516, 256, 0, stream>>>(x, Wo, Wq, bq, Wk, bk, Wv, bv, Xb, Wob, Wt, ball);
  // QKV: BN=96 -> 32x32 = 1024 blocks = 4 blocks/CU
  gemm_bt<96, true, false, u16><<<1024, 256, 0, stream>>>(Xb, Wt, ball, QKV, Vtc,
                                                          4096, 3072, 1024, 1024, qscale);
  attn_kernel<<<1024, 256, 0, stream>>>(QKV, Vtc, Ob);
  // out-proj: BM=64 tiles -> 1024 blocks = 4 blocks/CU (was 512 = 2/CU)
  gemm_out64<<<1024, 256, 0, stream>>>(Ob, Wob, bo, (float*)d_out);
}

// Round 8
// 188.387 us; speedup vs baseline: 1.0342x; 1.0342x over previous
//
#include <hip/hip_runtime.h>
#include <hip/hip_bf16.h>

typedef unsigned short u16;
typedef short short8 __attribute__((ext_vector_type(8)));
typedef float floatx4 __attribute__((ext_vector_type(4)));

#define MFMA16(a, b, c) __builtin_amdgcn_mfma_f32_16x16x32_bf16((a), (b), (c), 0, 0, 0)

union U128u { uint4 q; u16 s[8]; };

__device__ __forceinline__ u16 f2bf(float f) {
  union { float f; unsigned u; } v; v.f = f;
  unsigned r = v.u + 0x7fffu + ((v.u >> 16) & 1u);
  return (u16)(r >> 16);
}

__device__ __forceinline__ float bf2f(u16 s) {
  union { unsigned u; float f; } v; v.u = ((unsigned)s) << 16;
  return v.f;
}

// pack two f32 -> bf16x2 (round-half-up) with one v_perm (attn P only)
__device__ __forceinline__ unsigned pk2(float hi, float lo) {
  union { float f; unsigned u; } a, b;
  a.f = hi; b.f = lo;
  return __builtin_amdgcn_perm(a.u + 0x8000u, b.u + 0x8000u, 0x07060302u);
}

__device__ __forceinline__ float fexp2(float x) {
#if __has_builtin(__builtin_amdgcn_exp2f)
  return __builtin_amdgcn_exp2f(x);
#else
  return exp2f(x);
#endif
}

// async global->LDS, 16B per lane. lds pointer must be wave-uniform. (GEMMs only.)
__device__ __forceinline__ void async16(const u16* g, u16* l) {
  __builtin_amdgcn_global_load_lds(
      (const __attribute__((address_space(1))) unsigned int*)g,
      (__attribute__((address_space(3))) unsigned int*)l, 16, 0, 0);
}

// ---------------- merged prep: cast x, cast Wo, repack Wqkv + biases ----------------
// r7 LESSON: the scalar u16 Wt stores at 8KB stride are ABSORBED BY L2 (write-back; Wt
// 6MB < 32MB aggregate) -- no HBM write amplification. The r7 "fix" (384 fat LDS-transpose
// blocks, 1.5/CU, two serial phases) was 6 us SLOWER than this streaming form. Reverted.

__global__ __launch_bounds__(256) void prep_all(
    const float* __restrict__ x, const float* __restrict__ Wo,
    const float* __restrict__ Wq, const float* __restrict__ bq,
    const float* __restrict__ Wk, const float* __restrict__ bk,
    const float* __restrict__ Wv, const float* __restrict__ bv,
    u16* __restrict__ Xb, u16* __restrict__ Wob,
    u16* __restrict__ Wt, float* __restrict__ ball) {
  int bid = blockIdx.x;
  int tid = threadIdx.x;
  if (bid < 5120) {
    // cast: blocks [0,4096) -> x (1048576 float4), [4096,5120) -> Wo (262144 float4)
    const float* src = bid < 4096 ? x : Wo;
    u16* dst = bid < 4096 ? Xb : Wob;
    int i = (bid < 4096 ? bid : bid - 4096) * 256 + tid;
    float4 v = ((const float4*)src)[i];
    union { unsigned long long ll; u16 s[4]; } o;
    o.s[0] = f2bf(v.x); o.s[1] = f2bf(v.y); o.s[2] = f2bf(v.z); o.s[3] = f2bf(v.w);
    ((unsigned long long*)dst)[i] = o.ll;
    return;
  }
  int id = (bid - 5120) * 256 + tid;  // 786432 total
  int kk4 = id & 15;
  int d = (id >> 4) & 1023;
  int h = (id >> 14) & 15;
  int wsel = id >> 18;
  const float* W = wsel == 0 ? Wq : (wsel == 1 ? Wk : Wv);
  float4 v = *(const float4*)(W + ((size_t)(h * 1024 + d)) * 64 + kk4 * 4);
  int nb = wsel * 1024 + h * 64 + kk4 * 4;
  Wt[(size_t)(nb + 0) * 1024 + d] = f2bf(v.x);
  Wt[(size_t)(nb + 1) * 1024 + d] = f2bf(v.y);
  Wt[(size_t)(nb + 2) * 1024 + d] = f2bf(v.z);
  Wt[(size_t)(nb + 3) * 1024 + d] = f2bf(v.w);
  if (id < 3072) {
    int ws2 = id >> 10, hk = id & 1023;
    const float* bsrc = ws2 == 0 ? bq : (ws2 == 1 ? bk : bv);
    ball[id] = bsrc[hk];
  }
}

// ---------------- GEMM: C[M,N] = A[M,K] * B^T (B stored [N,K]) + bias, opt scale --------------
// r8: QKV tile BN 96 -> 128 (m97 geometry: 16 MFMAs per 256 staged LDS rows vs 12/224,
// +17% arithmetic intensity; this exact structure = ~900 TF on the ladder). Grid 32x24 =
// 768 blocks = exactly 3/CU, no tail. Bounds (256,3): ~120 regs fits the 3-wave quantum
// (<=170); (256,4)'s 128-reg cap would risk the r1/r3/r4 spill disease.

__device__ __forceinline__ void store_out(u16* p, float v) { *p = f2bf(v); }
__device__ __forceinline__ void store_out(float* p, float v) { *p = v; }

template <int BN, bool SPLITV, bool TRANS, typename OutT>
__global__ __launch_bounds__(256, 3) void gemm_bt(
    const u16* __restrict__ A, const u16* __restrict__ B,
    const float* __restrict__ bias, OutT* __restrict__ C,
    u16* __restrict__ Vtc,
    int M, int N, int K, int scaleNend, float scaleVal) {
  constexpr int TN = BN / 32;  // n-tiles per wave
  __shared__ __attribute__((aligned(16))) u16 As[128 * 64];
  __shared__ __attribute__((aligned(16))) u16 Bs[BN * 64];
  const int tid = threadIdx.x;
  const int w = tid >> 6, lane = tid & 63;
  const int l15 = lane & 15, l4 = lane >> 4;
  const int lin = blockIdx.x;
  const int xcd = lin & 7, sblk = lin >> 3;
  const int bm = xcd * 4 + (sblk & 3);   // M=4096 -> 32 bm tiles, 4 per XCD
  const int bn = sblk >> 2;
  const int wm = (w & 1) * 64, wn = (w >> 1) * (BN / 2);

  floatx4 acc[4][TN];
#pragma unroll
  for (int i = 0; i < 4; ++i)
#pragma unroll
    for (int j = 0; j < TN; ++j) acc[i][j] = (floatx4){0.f, 0.f, 0.f, 0.f};

  for (int k0 = 0; k0 < K; k0 += 64) {
    __syncthreads();
#pragma unroll
    for (int j = 0; j < 4; ++j) {  // A: 128 rows x 8 chunks = 1024 slots
      int i = j * 256 + tid;
      int row = i >> 3, c = (i & 7) ^ (row & 7);
      async16(A + (size_t)(bm * 128 + row) * K + k0 + c * 8, As + (j * 256 + w * 64) * 8);
    }
#pragma unroll
    for (int j = 0; j < BN / 32; ++j) {  // B: BN rows x 8 chunks
      int i = j * 256 + tid;
      int row = i >> 3, c = (i & 7) ^ (row & 7);
      async16(B + (size_t)(bn * BN + row) * K + k0 + c * 8, Bs + (j * 256 + w * 64) * 8);
    }
    __syncthreads();
    const int sw = l15 & 7;
#pragma unroll
    for (int ks = 0; ks < 2; ++ks) {
      short8 af[4], bf[TN];
#pragma unroll
      for (int t = 0; t < 4; ++t)
        af[t] = *(const short8*)(As + (wm + t * 16 + l15) * 64 + (((ks * 4 + l4) ^ sw)) * 8);
#pragma unroll
      for (int t = 0; t < TN; ++t)
        bf[t] = *(const short8*)(Bs + (wn + t * 16 + l15) * 64 + (((ks * 4 + l4) ^ sw)) * 8);
#pragma unroll
      for (int tm = 0; tm < 4; ++tm)
#pragma unroll
        for (int tn = 0; tn < TN; ++tn)
          acc[tm][tn] = TRANS ? MFMA16(bf[tn], af[tm], acc[tm][tn])
                              : MFMA16(af[tm], bf[tn], acc[tm][tn]);
    }
  }

  if (TRANS) {
    // acc holds transposed fragments: lane l15 -> row (A index), l4*4+r -> col (B index)
#pragma unroll
    for (int tn = 0; tn < TN; ++tn) {
      int colb = bn * BN + wn + tn * 16 + l4 * 4;
      float4 bv4 = *(const float4*)(bias + colb);
#pragma unroll
      for (int tm = 0; tm < 4; ++tm) {
        int row = bm * 128 + wm + tm * 16 + l15;
        float4 v;
        v.x = acc[tm][tn][0] + bv4.x;
        v.y = acc[tm][tn][1] + bv4.y;
        v.z = acc[tm][tn][2] + bv4.z;
        v.w = acc[tm][tn][3] + bv4.w;
        *(float4*)((float*)C + (size_t)row * N + colb) = v;
      }
    }
    return;
  }

#pragma unroll
  for (int tn = 0; tn < TN; ++tn) {
    int col = bn * BN + wn + tn * 16 + l15;
    float bv = bias[col];
    float sc = (col < scaleNend) ? scaleVal : 1.0f;
    if (!SPLITV || col < 2048) {
#pragma unroll
      for (int tm = 0; tm < 4; ++tm) {
        int row0 = bm * 128 + wm + tm * 16 + l4 * 4;
#pragma unroll
        for (int r = 0; r < 4; ++r) {
          float v = (acc[tm][tn][r] + bv) * sc;
          store_out(C + (size_t)(row0 + r) * N + col, v);
        }
      }
    } else {
      int hv = (col - 2048) >> 6, d = (col - 2048) & 63;
#pragma unroll
      for (int tm = 0; tm < 4; ++tm) {
        int row0 = bm * 128 + wm + tm * 16 + l4 * 4;
        int bb = row0 >> 11, s0 = row0 & 2047;
        union { unsigned long long ll; u16 s[4]; } o;
#pragma unroll
        for (int r = 0; r < 4; ++r) o.s[r] = f2bf(acc[tm][tn][r] + bv);
        // rows row0..row0+3 are consecutive (s&7) slots of one octet -> one 8B store
        size_t idx = ((((size_t)(bb * 16 + hv) * 128 + (s0 >> 4)) * 2 + ((s0 >> 3) & 1)) * 64 + d) * 8 +
                     (s0 & 7);
        *(unsigned long long*)(Vtc + idx) = o.ll;
      }
    }
  }
}

// ---------------- out-proj GEMM: BM=64, BN=64 -> 1024 blocks = 4 blocks/CU ----------------
__global__ __launch_bounds__(256, 4) void gemm_out64(
    const u16* __restrict__ A, const u16* __restrict__ B,
    const float* __restrict__ bias, float* __restrict__ C) {
  __shared__ __attribute__((aligned(16))) u16 As[64 * 64];
  __shared__ __attribute__((aligned(16))) u16 Bs[64 * 64];
  const int tid = threadIdx.x;
  const int w = tid >> 6, lane = tid & 63;
  const int l15 = lane & 15, l4 = lane >> 4;
  const int lin = blockIdx.x;                // 1024 blocks
  const int xcd = lin & 7, sblk = lin >> 3;  // sblk in [0,128)
  const int bm = xcd * 8 + (sblk & 7);       // 64 bm tiles, 8 per XCD
  const int bn = sblk >> 3;                  // 16 bn tiles
  const int wm = (w & 1) * 32, wn = (w >> 1) * 32;

  floatx4 acc[2][2];
#pragma unroll
  for (int i = 0; i < 2; ++i)
#pragma unroll
    for (int j = 0; j < 2; ++j) acc[i][j] = (floatx4){0.f, 0.f, 0.f, 0.f};

  for (int k0 = 0; k0 < 1024; k0 += 64) {
    __syncthreads();
#pragma unroll
    for (int j = 0; j < 2; ++j) {  // A: 64 rows x 8 chunks = 512 slots
      int i = j * 256 + tid;
      int row = i >> 3, c = (i & 7) ^ (row & 7);
      async16(A + (size_t)(bm * 64 + row) * 1024 + k0 + c * 8, As + (j * 256 + w * 64) * 8);
    }
#pragma unroll
    for (int j = 0; j < 2; ++j) {  // B: 64 rows x 8 chunks
      int i = j * 256 + tid;
      int row = i >> 3, c = (i & 7) ^ (row & 7);
      async16(B + (size_t)(bn * 64 + row) * 1024 + k0 + c * 8, Bs + (j * 256 + w * 64) * 8);
    }
    __syncthreads();
    const int sw = l15 & 7;
#pragma unroll
    for (int ks = 0; ks < 2; ++ks) {
      short8 af[2], bf[2];
#pragma unroll
      for (int t = 0; t < 2; ++t)
        af[t] = *(const short8*)(As + (wm + t * 16 + l15) * 64 + (((ks * 4 + l4) ^ sw)) * 8);
#pragma unroll
      for (int t = 0; t < 2; ++t)
        bf[t] = *(const short8*)(Bs + (wn + t * 16 + l15) * 64 + (((ks * 4 + l4) ^ sw)) * 8);
#pragma unroll
      for (int tm = 0; tm < 2; ++tm)
#pragma unroll
        for (int tn = 0; tn < 2; ++tn)
          acc[tm][tn] = MFMA16(bf[tn], af[tm], acc[tm][tn]);  // TRANS order
    }
  }

  // TRANS epilogue: lane l15 -> C row, l4*4+r -> C col; float4 stores
#pragma unroll
  for (int tn = 0; tn < 2; ++tn) {
    int colb = bn * 64 + wn + tn * 16 + l4 * 4;
    float4 bv4 = *(const float4*)(bias + colb);
#pragma unroll
    for (int tm = 0; tm < 2; ++tm) {
      int row = bm * 64 + wm + tm * 16 + l15;
      float4 v;
      v.x = acc[tm][tn][0] + bv4.x;
      v.y = acc[tm][tn][1] + bv4.y;
      v.z = acc[tm][tn][2] + bv4.z;
      v.w = acc[tm][tn][3] + bv4.w;
      *(float4*)(C + (size_t)row * 1024 + colb) = v;
    }
  }
}

// ---------------- attention v7 (kept from r7): r5 skew + l-SUM VIA MFMA ONES-COLUMN ----------
// OCCUPANCY VERDICT (r1/r3/r4): 64q x 512k wave tile needs ~148-160 regs; 12 waves/CU is
// the ceiling. TILING (r2): smaller wave tiles halve K/V reuse; 1.8x worse. SKEW (r5):
// S^T(c) -> P-buf[c&1] while PV(c-1) drains the other; +6 us. PREFETCH (r6): kf register
// prefetch NULL (+scratch) -- at this pressure, added pipeline state is self-defeating.
// ONES-COLUMN (r7, kept): lpart add-chain moved to matrix pipe via vone B-frag; -2 us,
// gates clean (FETCH 12.6 / WRITE 8.2 MB).
__global__ __launch_bounds__(256, 3) void attn_kernel(const u16* __restrict__ QKV,
                                                      const u16* __restrict__ Vtc,
                                                      u16* __restrict__ Ob) {
  // per-wave region: 5120 u16 = P double-buffer [2][64 q][stride 40] (2x2560),
  // overlaid post-loop by Osum bf16 [64][stride 72] (4608) + l f32[64] at 4608.
  __shared__ __attribute__((aligned(16))) u16 lds[4 * 5120];  // 40960 B
  const int tid = threadIdx.x;
  const int w = tid >> 6, lane = tid & 63;
  const int l15 = lane & 15, l4 = lane >> 4;
  const int lin = blockIdx.x;                 // 1024 blocks
  const int xcd = lin & 7, sblk = lin >> 3;   // sblk in [0,128)
  const int bh = xcd * 4 + (sblk & 3);        // 4 bh per XCD
  const int q0 = (sblk >> 2) * 64;            // 32 q-tiles of 64
  const int b = bh >> 4, h = bh & 15;

  u16* const Pw = lds + w * 5120;

  // Q fragments (B-operand of S^T): rows q0 + tq*16 + l15, k(d) = s*32 + l4*8
  short8 qf[4][2];
  {
    const u16* Qb = QKV + (size_t)(b * 2048 + q0) * 3072 + h * 64;
#pragma unroll
    for (int tq = 0; tq < 4; ++tq)
#pragma unroll
      for (int s = 0; s < 2; ++s)
        qf[tq][s] = *(const short8*)(Qb + (size_t)(tq * 16 + l15) * 3072 + s * 32 + l4 * 8);
  }

  floatx4 Oacc[4][4];
#pragma unroll
  for (int i = 0; i < 4; ++i)
#pragma unroll
    for (int j = 0; j < 4; ++j) Oacc[i][j] = (floatx4){0.f, 0.f, 0.f, 0.f};
  floatx4 acc_l[4];
#pragma unroll
  for (int i = 0; i < 4; ++i) acc_l[i] = (floatx4){0.f, 0.f, 0.f, 0.f};

  // ones-column B fragment: B[n][k] = 1.0 iff n == 0 (lane n = l15, k = l4*8+j)
  short8 vone;
  {
    u16 one = (l15 == 0) ? (u16)0x3F80 : (u16)0;
#pragma unroll
    for (int j = 0; j < 8; ++j) vone[j] = (short)one;
  }

  const u16* const Kb = QKV + (size_t)(b * 2048) * 3072 + 1024 + h * 64;  // + key*3072
  const u16* const Vw = Vtc + (size_t)bh * 131072 + (size_t)w * 32768;    // wave's 512 keys
  const int kw0 = w * 512;

  // ---- S^T for one 32-key superstep c into P buffer pb ----
  auto do_st = [&](int c, u16* pb) {
    const int key0 = kw0 + c * 32;
    short8 kf[2][2];
#pragma unroll
    for (int t = 0; t < 2; ++t)
#pragma unroll
      for (int s = 0; s < 2; ++s)
        kf[t][s] = *(const short8*)(Kb + (size_t)(key0 + t * 16 + l15) * 3072 + s * 32 + l4 * 8);
#pragma unroll
    for (int t = 0; t < 2; ++t)
#pragma unroll
      for (int tq = 0; tq < 4; ++tq) {
        floatx4 s = (floatx4){0.f, 0.f, 0.f, 0.f};
        s = MFMA16(kf[t][0], qf[tq][0], s);
        s = MFMA16(kf[t][1], qf[tq][1], s);
        float p0 = fexp2(s[0]), p1 = fexp2(s[1]), p2 = fexp2(s[2]), p3 = fexp2(s[3]);
        unsigned lo = pk2(p1, p0), hi = pk2(p3, p2);
        *(unsigned long long*)(pb + (size_t)(tq * 16 + l15) * 40 + t * 16 + l4 * 4) =
            ((unsigned long long)hi << 32) | lo;
      }
  };

  // ---- PV for superstep c from P buffer pb; l-sum rides the matrix pipe ----
  auto do_pv = [&](int c, const u16* pb) {
    short8 vf[4];
#pragma unroll
    for (int td = 0; td < 4; ++td)
      vf[td] = *(const short8*)(Vw + (size_t)c * 2048 + l4 * 512 + (td * 16 + l15) * 8);
    short8 pf[4];
#pragma unroll
    for (int tq = 0; tq < 4; ++tq)
      pf[tq] = *(const short8*)(pb + (size_t)(tq * 16 + l15) * 40 + l4 * 8);
#pragma unroll
    for (int td = 0; td < 4; ++td)
#pragma unroll
      for (int tq = 0; tq < 4; ++tq) Oacc[tq][td] = MFMA16(pf[tq], vf[td], Oacc[tq][td]);
#pragma unroll
    for (int tq = 0; tq < 4; ++tq) acc_l[tq] = MFMA16(pf[tq], vone, acc_l[tq]);
  };

  // prologue: fill P buffer 0
  do_st(0, Pw);
  // steady state: S^T(c) -> buf[c&1] while PV(c-1) drains buf[(c-1)&1]
#pragma unroll 1
  for (int c = 1; c < 16; ++c) {
    do_st(c, Pw + (c & 1) * 2560);
    do_pv(c - 1, Pw + ((c - 1) & 1) * 2560);
  }
  // epilogue
  do_pv(15, Pw + 2560);

  // write per-wave partials (own region; own P reads already retired in-order)
#pragma unroll
  for (int tq = 0; tq < 4; ++tq)
#pragma unroll
    for (int td = 0; td < 4; ++td)
#pragma unroll
      for (int r = 0; r < 4; ++r)
        Pw[(size_t)(tq * 16 + l4 * 4 + r) * 72 + td * 16 + l15] = f2bf(Oacc[tq][td][r]);
  if (l15 == 0) {  // acc_l column 0 lives in lanes l15==0; rows q = tq*16 + l4*4 + r
    float* Lw = (float*)(Pw + 4608);
#pragma unroll
    for (int tq = 0; tq < 4; ++tq)
#pragma unroll
      for (int r = 0; r < 4; ++r) Lw[tq * 16 + l4 * 4 + r] = acc_l[tq][r];
  }
  __syncthreads();

  // combine: thread -> (row = tid>>2 of 64, 16 cols); sum 4 wave partials
  {
    int row = tid >> 2, c0 = (tid & 3) * 16;
    float acc[16];
#pragma unroll
    for (int j = 0; j < 16; ++j) acc[j] = 0.f;
    float lsum = 0.f;
#pragma unroll
    for (int wv = 0; wv < 4; ++wv) {
      const u16* R = lds + wv * 5120;
      lsum += ((const float*)(R + 4608))[row];
      U128u x1, x2;
      x1.q = *(const uint4*)(R + (size_t)row * 72 + c0);
      x2.q = *(const uint4*)(R + (size_t)row * 72 + c0 + 8);
#pragma unroll
      for (int j = 0; j < 8; ++j) { acc[j] += bf2f(x1.s[j]); acc[8 + j] += bf2f(x2.s[j]); }
    }
    float inv = 1.0f / lsum;
    U128u o1, o2;
#pragma unroll
    for (int j = 0; j < 8; ++j) { o1.s[j] = f2bf(acc[j] * inv); o2.s[j] = f2bf(acc[8 + j] * inv); }
    u16* Op = Ob + (size_t)(b * 2048 + q0 + row) * 1024 + h * 64 + c0;
    *(uint4*)Op = o1.q;
    *(uint4*)(Op + 8) = o2.q;
  }
}

// ---------------- launch ----------------

extern "C" void kernel_launch(void* const* d_in, const int* in_sizes, int n_in,
                              void* d_out, int out_size, void* d_ws, size_t ws_size,
                              hipStream_t stream) {
  const float* x  = (const float*)d_in[0];
  const float* Wq = (const float*)d_in[1];
  const float* bq = (const float*)d_in[2];
  const float* Wk = (const float*)d_in[3];
  const float* bk = (const float*)d_in[4];
  const float* Wv = (const float*)d_in[5];
  const float* bv = (const float*)d_in[6];
  const float* Wo = (const float*)d_in[7];
  const float* bo = (const float*)d_in[8];

  char* p = (char*)d_ws;
  u16* Xb   = (u16*)p; p += (size_t)4096 * 1024 * 2;   // x bf16
  u16* Wt   = (u16*)p; p += (size_t)3072 * 1024 * 2;   // W_all^T bf16 [n][d]
  u16* QKV  = (u16*)p; p += (size_t)4096 * 3072 * 2;   // [token][3072] bf16; Q pre-scaled, V third unused
  u16* Vtc  = (u16*)p; p += (size_t)32 * 128 * 2 * 64 * 8 * 2;  // V chunked: [bh][v][o][d][k8]
  u16* Ob   = (u16*)p; p += (size_t)4096 * 1024 * 2;   // attention out bf16 (normalized)
  u16* Wob  = (u16*)p; p += (size_t)1024 * 1024 * 2;   // Wo bf16 [e][d]
  float* ball = (float*)p; p += 3072 * sizeof(float);

  const float qscale = 0.125f * 1.4426950408889634f;  // (1/sqrt(64)) * log2(e)

  prep_all<<<8192, 256, 0, stream>>>(x, Wo, Wq, bq, Wk, bk, Wv, bv, Xb, Wob, Wt, ball);
  // QKV: BN=128 (m97 geometry) -> 32x24 = 768 blocks = exactly 3 blocks/CU, no tail
  gemm_bt<128, true, false, u16><<<768, 256, 0, stream>>>(Xb, Wt, ball, QKV, Vtc,
                                                          4096, 3072, 1024, 1024, qscale);
  attn_kernel<<<1024, 256, 0, stream>>>(QKV, Vtc, Ob);
  // out-proj: BM=64 tiles -> 1024 blocks = 4 blocks/CU
  gemm_out64<<<1024, 256, 0, stream>>>(Ob, Wob, bo, (float*)d_out);
}